// Round 4
// baseline (1895.518 us; speedup 1.0000x reference)
//
#include <hip/hip_runtime.h>

#define BB 8192
#define TT 10
#define FF 561
#define FP 576   // 561 padded to 18*32
#define HH 256
#define OO 12

typedef __attribute__((ext_vector_type(8))) __bf16 bf16x8;
typedef __attribute__((ext_vector_type(4))) float f32x4;

__device__ __forceinline__ unsigned short f2bf(float f) {
  unsigned int u = __float_as_uint(f);
  u += 0x7fffu + ((u >> 16) & 1u);   // round-to-nearest-even
  return (unsigned short)(u >> 16);
}
__device__ __forceinline__ float sigm(float x) { return 1.f / (1.f + __expf(-x)); }
__device__ __forceinline__ float tanh_fast(float x) { return 1.f - 2.f / (__expf(2.f * x) + 1.f); }

__device__ __forceinline__ void gl_lds16(const unsigned short* g, unsigned short* l) {
  __builtin_amdgcn_global_load_lds(
      (const __attribute__((address_space(1))) unsigned int*)g,
      (__attribute__((address_space(3))) unsigned int*)l, 16, 0, 0);
}

// 128x128 tile worth of MFMA from one LDS A/B buffer (BK=32)
__device__ __forceinline__ void mfma_tile(const unsigned short* as, const unsigned short* bs,
                                          int w, int quad, int l15, f32x4 (&acc)[2][8]) {
  bf16x8 af[2], bfr[8];
#pragma unroll
  for (int mt = 0; mt < 2; ++mt)
    af[mt] = *(const bf16x8*)&as[(w * 32 + mt * 16 + l15) * 32 + quad * 8];
#pragma unroll
  for (int nt = 0; nt < 8; ++nt)
    bfr[nt] = *(const bf16x8*)&bs[(nt * 16 + l15) * 32 + quad * 8];
#pragma unroll
  for (int mt = 0; mt < 2; ++mt)
#pragma unroll
    for (int nt = 0; nt < 8; ++nt)
      acc[mt][nt] = __builtin_amdgcn_mfma_f32_16x16x32_bf16(af[mt], bfr[nt], acc[mt][nt], 0, 0, 0);
}

// Convert inputs [81920,561] f32 -> bf16 zero-padded [81920,576]
__global__ void conv_inputs(const float* __restrict__ in, unsigned short* __restrict__ Ain) {
  int idx = blockIdx.x * 256 + threadIdx.x;  // over 81920*144, 4 elems each
  if (idx >= 81920 * 144) return;
  int c4 = (idx % 144) * 4;
  size_t row = idx / 144;
  const float* src = in + row * 561 + c4;
  ushort4 v;
  v.x = f2bf(c4 + 0 < 561 ? src[0] : 0.f);
  v.y = f2bf(c4 + 1 < 561 ? src[1] : 0.f);
  v.z = f2bf(c4 + 2 < 561 ? src[2] : 0.f);
  v.w = f2bf(c4 + 3 < 561 ? src[3] : 0.f);
  *(ushort4*)(Ain + row * 576 + c4) = v;
}

// Build bf16 weights (layouts unchanged from round 0)
__global__ void conv_weights(const float* __restrict__ Winp,
                             const float* __restrict__ Wih0, const float* __restrict__ Whh0,
                             const float* __restrict__ Wih1, const float* __restrict__ Whh1,
                             const float* __restrict__ Wout,
                             unsigned short* __restrict__ Wib,
                             unsigned short* __restrict__ W0p,
                             unsigned short* __restrict__ W1p,
                             unsigned short* __restrict__ Wob) {
  int idx = blockIdx.x * 256 + threadIdx.x;
  if (idx < 256 * 576) {
    int kk = idx % 576, n = idx / 576;
    Wib[idx] = f2bf(kk < 561 ? Winp[n * 561 + kk] : 0.f);
    return;
  }
  idx -= 256 * 576;
  if (idx < 1024 * 512) {
    int kk = idx % 512, np = idx / 512;
    int h = (np >> 7) * 32 + (np & 31), g = (np >> 5) & 3;
    int sr = g * 256 + h;
    float v = kk < 256 ? Wih0[sr * 256 + kk] : Whh0[sr * 256 + kk - 256];
    W0p[idx] = f2bf(v);
    return;
  }
  idx -= 1024 * 512;
  if (idx < 1024 * 512) {
    int kk = idx % 512, np = idx / 512;
    int h = (np >> 7) * 32 + (np & 31), g = (np >> 5) & 3;
    int sr = g * 256 + h;
    float v = kk < 256 ? Wih1[sr * 256 + kk] : Whh1[sr * 256 + kk - 256];
    W1p[idx] = f2bf(v);
    return;
  }
  idx -= 1024 * 512;
  if (idx < 16 * 256) {
    int kk = idx % 256, o = idx / 256;
    Wob[idx] = f2bf(o < OO ? Wout[o * 256 + kk] : 0.f);
  }
}

// xp GEMM: xp[81920,256] = Ain @ Wib^T + b_inp. M=81920 N=256 K=576. (unchanged)
__global__ __launch_bounds__(256, 2) void gemm_xp(
    const unsigned short* __restrict__ A, const unsigned short* __restrict__ W,
    const float* __restrict__ bias, unsigned short* __restrict__ xp) {
  __shared__ __align__(16) unsigned short As[2][128 * 32];
  __shared__ __align__(16) unsigned short Bs[2][128 * 32];
  const int tid = threadIdx.x;
  const int w = tid >> 6, lane = tid & 63, quad = lane >> 4, l15 = lane & 15;
  const int flat = blockIdx.x;
  const int xcd = flat & 7, kb = flat >> 3;     // kb in [0,160)
  const int nb = kb & 1, mb = xcd * 80 + (kb >> 1);
  const int r0 = tid >> 2, cc = (tid & 3) * 8;

  auto stage = [&](int buf, int k0) {
    gl_lds16(A + (size_t)(mb * 128 + r0) * FP + k0 + cc, &As[buf][tid * 8]);
    gl_lds16(A + (size_t)(mb * 128 + 64 + r0) * FP + k0 + cc, &As[buf][2048 + tid * 8]);
    gl_lds16(W + (size_t)(nb * 128 + r0) * FP + k0 + cc, &Bs[buf][tid * 8]);
    gl_lds16(W + (size_t)(nb * 128 + 64 + r0) * FP + k0 + cc, &Bs[buf][2048 + tid * 8]);
  };

  f32x4 acc[2][8];
#pragma unroll
  for (int i = 0; i < 2; ++i)
#pragma unroll
    for (int j = 0; j < 8; ++j) acc[i][j] = (f32x4){0.f, 0.f, 0.f, 0.f};

  stage(0, 0);
  __syncthreads();
  int cur = 0;
#pragma unroll
  for (int ks = 0; ks < 17; ++ks) {
    stage(cur ^ 1, (ks + 1) * 32);
    mfma_tile(&As[cur][0], &Bs[cur][0], w, quad, l15, acc);
    __syncthreads();
    cur ^= 1;
  }
  mfma_tile(&As[cur][0], &Bs[cur][0], w, quad, l15, acc);

#pragma unroll
  for (int mt = 0; mt < 2; ++mt) {
    int rowb = mb * 128 + w * 32 + mt * 16 + quad * 4;
#pragma unroll
    for (int nt = 0; nt < 8; ++nt) {
      int col = nb * 128 + nt * 16 + l15;
      float bv = bias[col];
#pragma unroll
      for (int r = 0; r < 4; ++r)
        xp[(size_t)(rowb + r) * HH + col] = f2bf(acc[mt][nt][r] + bv);
    }
  }
}

struct PArgs {
  const unsigned short* xp;   // [81920][256], row m = b*TT + t
  unsigned short* h0s;        // [2][B][H] ping-pong, slot 0 zeroed
  unsigned short* hs;         // [(T+1)][B][H], slot 0 zeroed
  const unsigned short* W0p;  // [1024][512] gate-permuted
  const unsigned short* W1p;
  const float *bih0, *bhh0, *bih1, *bhh1;
  float* hn;                  // [2][B][H] f32 out
  float* cn;                  // [2][B][H] f32 out
  unsigned int* flags;        // [64 groups][64] zeroed
};

// Persistent LSTM: all T=10 steps, both layers, ONE plain launch (graph-capturable;
// cooperative launch was silently dropped by the capture path in round 2).
// Grid 512 = exact device capacity (64KB LDS + launch_bounds(256,2) => 2 blocks/CU).
// Group = 8 CONTIGUOUS blocks [8g, 8g+8): block handles rows [128g,128g+128),
// h-col slice [32nb,32nb+32), nb = flat&7. Contiguity => any in-order prefix of
// dispatched blocks contains whole groups => no cross-group deadlock even under
// partial residency. One flag barrier per timestep (after L0); L1(t)->L0(t+1)
// needs none (program order: passing barrier(t) implies L1(t-1) done).
// Cell state c0/c1 lives in LDS (block-private across all t).
__global__ __launch_bounds__(256, 2) void lstm_persist(PArgs p) {
  __shared__ __align__(16) unsigned short As[2][128 * 32];
  __shared__ __align__(16) unsigned short Bs[2][128 * 32];
  __shared__ float c0l[128 * 32];
  __shared__ float c1l[128 * 32];
  const int tid = threadIdx.x;
  const int w = tid >> 6, lane = tid & 63, quad = lane >> 4, l15 = lane & 15;
  const int flat = blockIdx.x;
  const int nb = flat & 7, mb = flat >> 3;
  const int r0 = tid >> 2, cc = (tid & 3) * 8;
  unsigned int* flag = p.flags + mb * 64;

  for (int i = tid; i < 128 * 32; i += 256) { c0l[i] = 0.f; c1l[i] = 0.f; }

  auto stageA = [&](const unsigned short* src, int ld, int kk, int buf) {
    gl_lds16(src + (size_t)(mb * 128 + r0) * ld + kk + cc, &As[buf][tid * 8]);
    gl_lds16(src + (size_t)(mb * 128 + 64 + r0) * ld + kk + cc, &As[buf][2048 + tid * 8]);
  };
  auto stageB = [&](const unsigned short* W, int k0, int buf) {
    gl_lds16(W + (size_t)(nb * 128 + r0) * 512 + k0 + cc, &Bs[buf][tid * 8]);
    gl_lds16(W + (size_t)(nb * 128 + 64 + r0) * 512 + k0 + cc, &Bs[buf][2048 + tid * 8]);
  };

  auto epilogue = [&](f32x4 (&acc)[2][8], const float* bA, const float* bB,
                      float* cl, unsigned short* hout, float* hf, float* cf) {
#pragma unroll
    for (int hb = 0; hb < 2; ++hb) {
      const int hg = nb * 32 + hb * 16 + l15;
      const float bI = bA[hg] + bB[hg];
      const float bF = bA[256 + hg] + bB[256 + hg];
      const float bG = bA[512 + hg] + bB[512 + hg];
      const float bO = bA[768 + hg] + bB[768 + hg];
#pragma unroll
      for (int mt = 0; mt < 2; ++mt) {
        const int rl = w * 32 + mt * 16 + quad * 4;
#pragma unroll
        for (int r = 0; r < 4; ++r) {
          const int lidx = (rl + r) * 32 + hb * 16 + l15;
          const size_t gidx = (size_t)(mb * 128 + rl + r) * HH + hg;
          const float xi = acc[mt][0 + hb][r] + bI;
          const float xf = acc[mt][2 + hb][r] + bF;
          const float xg = acc[mt][4 + hb][r] + bG;
          const float xo = acc[mt][6 + hb][r] + bO;
          const float c_old = cl[lidx];
          const float cnv = sigm(xf) * c_old + sigm(xi) * tanh_fast(xg);
          const float hnv = sigm(xo) * tanh_fast(cnv);
          cl[lidx] = cnv;
          hout[gidx] = f2bf(hnv);
          if (hf) { hf[gidx] = hnv; cf[gidx] = cnv; }
        }
      }
    }
  };

  // prologue: L0(0) tile 0 (xp k-cols 0..31 + W0 k0=0)
  stageA(p.xp, TT * HH, 0, 0);
  stageB(p.W0p, 0, 0);

  unsigned int target = 0;
  for (int t = 0; t < TT; ++t) {
    const unsigned short* xpt = p.xp + (size_t)t * HH;
    const unsigned short* h0prev = p.h0s + (size_t)(t & 1) * BB * HH;
    unsigned short* h0new = p.h0s + (size_t)((t + 1) & 1) * BB * HH;
    const unsigned short* h1prev = p.hs + (size_t)t * BB * HH;
    unsigned short* h1new = p.hs + (size_t)(t + 1) * BB * HH;
    const bool last = (t == TT - 1);

    // ---------------- L0: gates = [xp_t | h0prev] @ W0^T ----------------
    f32x4 acc[2][8];
#pragma unroll
    for (int i = 0; i < 2; ++i)
#pragma unroll
      for (int j = 0; j < 8; ++j) acc[i][j] = (f32x4){0.f, 0.f, 0.f, 0.f};

    __syncthreads();   // tile 0 resident (barrier drains vmcnt)
    int cur = 0;
#pragma unroll
    for (int ks = 0; ks < 15; ++ks) {
      const int k0 = (ks + 1) * 32;
      if (k0 < 256) stageA(xpt, TT * HH, k0, cur ^ 1);
      else          stageA(h0prev, HH, k0 - 256, cur ^ 1);
      stageB(p.W0p, k0, cur ^ 1);
      mfma_tile(&As[cur][0], &Bs[cur][0], w, quad, l15, acc);
      __syncthreads();
      cur ^= 1;
    }
    mfma_tile(&As[cur][0], &Bs[cur][0], w, quad, l15, acc);   // tile 15, cur==1
    stageB(p.W1p, 256, 0);   // prefetch L1 tile0 B (L1 K-order starts at k0=256)

    epilogue(acc, p.bih0, p.bhh0, c0l, h0new,
             last ? p.hn : nullptr, last ? p.cn : nullptr);

    // ---- group barrier: release h0new to the 7 sibling blocks ----
    __threadfence();
    __syncthreads();
    ++target;                       // count goal = 8 * (t+1)
    if (tid == 0) {
      __hip_atomic_fetch_add(flag, 1u, __ATOMIC_RELEASE, __HIP_MEMORY_SCOPE_AGENT);
      long long spin0 = (long long)clock64();
      while (__hip_atomic_load(flag, __ATOMIC_ACQUIRE, __HIP_MEMORY_SCOPE_AGENT) < 8u * target) {
        __builtin_amdgcn_s_sleep(2);
        if ((long long)clock64() - spin0 > 100000000LL) break;  // anti-hang escape
      }
    }
    __syncthreads();
    __threadfence();

    // ---------------- L1: gates = [h0new | h1prev] @ W1^T ----------------
    // K-order: physical tiles 8..15 (h1prev half, B prefetched) then 0..7.
#pragma unroll
    for (int i = 0; i < 2; ++i)
#pragma unroll
      for (int j = 0; j < 8; ++j) acc[i][j] = (f32x4){0.f, 0.f, 0.f, 0.f};

    stageA(h1prev, HH, 0, 0);       // tile ks=8: A = h1prev k-cols 0..31
    __syncthreads();                // tile0 (A + prefetched B) resident
    cur = 0;
#pragma unroll
    for (int ls = 0; ls < 15; ++ls) {
      const int ks = (ls + 9) & 15;
      const int k0 = ks * 32;
      if (ks >= 8) stageA(h1prev, HH, k0 - 256, cur ^ 1);
      else         stageA(h0new, HH, k0, cur ^ 1);
      stageB(p.W1p, k0, cur ^ 1);
      mfma_tile(&As[cur][0], &Bs[cur][0], w, quad, l15, acc);
      __syncthreads();
      cur ^= 1;
    }
    mfma_tile(&As[cur][0], &Bs[cur][0], w, quad, l15, acc);   // cur==1
    if (t + 1 < TT) {               // prefetch L0(t+1) tile0 (xp + W0: both safe)
      stageA(p.xp + (size_t)(t + 1) * HH, TT * HH, 0, 0);
      stageB(p.W0p, 0, 0);
    }

    epilogue(acc, p.bih1, p.bhh1, c1l, h1new,
             last ? p.hn + (size_t)BB * HH : nullptr,
             last ? p.cn + (size_t)BB * HH : nullptr);
    // no barrier here: next consumer of h1new is L1(t+1), separated by the
    // t+1 group barrier; h0 ping-pong WAR covered by program order.
  }
}

// Output projection: out[m=t*B+b][o] = hs[m+B][:] . Wob[o][:] + bout[o] (unchanged)
__global__ __launch_bounds__(256) void out_gemm_mfma(
    const unsigned short* __restrict__ hs,
    const unsigned short* __restrict__ Wob,
    const float* __restrict__ bout,
    float* __restrict__ out) {
  const int tid = threadIdx.x;
  const int w = tid >> 6, lane = tid & 63, quad = lane >> 4, l15 = lane & 15;
  const int m0 = blockIdx.x * 64 + w * 16;
  const unsigned short* arow = hs + (size_t)(m0 + l15 + BB) * HH + quad * 8;
  const unsigned short* brow = Wob + l15 * HH + quad * 8;
  f32x4 acc = (f32x4){0.f, 0.f, 0.f, 0.f};
#pragma unroll
  for (int k0 = 0; k0 < 8; ++k0) {
    bf16x8 a = *(const bf16x8*)(arow + k0 * 32);
    bf16x8 b = *(const bf16x8*)(brow + k0 * 32);
    acc = __builtin_amdgcn_mfma_f32_16x16x32_bf16(a, b, acc, 0, 0, 0);
  }
  const int o = l15;
  if (o < OO) {
    float bv = bout[o];
#pragma unroll
    for (int r = 0; r < 4; ++r) {
      int m = m0 + quad * 4 + r;
      int b = m & (BB - 1);
      int t = m >> 13;
      out[((size_t)b * TT + t) * OO + o] = acc[r] + bv;
    }
  }
}

extern "C" void kernel_launch(void* const* d_in, const int* in_sizes, int n_in,
                              void* d_out, int out_size, void* d_ws, size_t ws_size,
                              hipStream_t stream) {
  const float* inputs = (const float*)d_in[0];
  const float* W_inp  = (const float*)d_in[1];
  const float* b_inp  = (const float*)d_in[2];
  const float* Wih0   = (const float*)d_in[3];
  const float* Whh0   = (const float*)d_in[4];
  const float* bih0   = (const float*)d_in[5];
  const float* bhh0   = (const float*)d_in[6];
  const float* Wih1   = (const float*)d_in[7];
  const float* Whh1   = (const float*)d_in[8];
  const float* bih1   = (const float*)d_in[9];
  const float* bhh1   = (const float*)d_in[10];
  const float* W_out  = (const float*)d_in[11];
  const float* b_out  = (const float*)d_in[12];
  float* out = (float*)d_out;

  char* ws = (char*)d_ws;
  size_t off = 0;
  auto alloc = [&](size_t bytes) {
    char* p = ws + off;
    off += (bytes + 255) & ~(size_t)255;
    return p;
  };
  unsigned short* Ain = (unsigned short*)alloc((size_t)81920 * FP * 2);
  unsigned short* xp  = (unsigned short*)alloc((size_t)81920 * HH * 2);
  unsigned short* Wib = (unsigned short*)alloc((size_t)256 * FP * 2);
  unsigned short* W0p = (unsigned short*)alloc((size_t)1024 * 512 * 2);
  unsigned short* W1p = (unsigned short*)alloc((size_t)1024 * 512 * 2);
  unsigned short* Wob = (unsigned short*)alloc((size_t)16 * HH * 2);
  unsigned short* h0s = (unsigned short*)alloc((size_t)2 * BB * HH * 2);
  unsigned short* hs  = (unsigned short*)alloc((size_t)(TT + 1) * BB * HH * 2);
  unsigned int* flags = (unsigned int*)alloc((size_t)64 * 64 * 4);

  hipMemsetAsync(h0s, 0, (size_t)BB * HH * 2, stream);   // slot 0 only
  hipMemsetAsync(hs, 0, (size_t)BB * HH * 2, stream);    // slot 0 only
  hipMemsetAsync(flags, 0, (size_t)64 * 64 * 4, stream);

  conv_inputs<<<(81920 * 144 + 255) / 256, 256, 0, stream>>>(inputs, Ain);
  {
    int nthr = 256 * 576 + 2 * 1024 * 512 + 16 * 256;
    conv_weights<<<(nthr + 255) / 256, 256, 0, stream>>>(W_inp, Wih0, Whh0, Wih1, Whh1,
                                                         W_out, Wib, W0p, W1p, Wob);
  }

  gemm_xp<<<1280, 256, 0, stream>>>(Ain, Wib, b_inp, xp);

  float* hn_out = out + (size_t)BB * TT * OO;       // h_n [2][B][H]
  float* cn_out = hn_out + (size_t)2 * BB * HH;     // c_n [2][B][H]

  PArgs pa;
  pa.xp = xp; pa.h0s = h0s; pa.hs = hs;
  pa.W0p = W0p; pa.W1p = W1p;
  pa.bih0 = bih0; pa.bhh0 = bhh0; pa.bih1 = bih1; pa.bhh1 = bhh1;
  pa.hn = hn_out; pa.cn = cn_out;
  pa.flags = flags;
  lstm_persist<<<512, 256, 0, stream>>>(pa);

  out_gemm_mfma<<<1280, 256, 0, stream>>>(hs, Wob, b_out, out);
}

// Round 5
// 1230.403 us; speedup vs baseline: 1.5406x; 1.5406x over previous
//
#include <hip/hip_runtime.h>

#define BB 8192
#define TT 10
#define FF 561
#define FP 576   // 561 padded to 18*32
#define HH 256
#define OO 12

typedef __attribute__((ext_vector_type(8))) __bf16 bf16x8;
typedef __attribute__((ext_vector_type(4))) float f32x4;

__device__ __forceinline__ unsigned short f2bf(float f) {
  unsigned int u = __float_as_uint(f);
  u += 0x7fffu + ((u >> 16) & 1u);   // round-to-nearest-even
  return (unsigned short)(u >> 16);
}
__device__ __forceinline__ float sigm(float x) { return 1.f / (1.f + __expf(-x)); }
__device__ __forceinline__ float tanh_fast(float x) { return 1.f - 2.f / (__expf(2.f * x) + 1.f); }

__device__ __forceinline__ void gl_lds16(const unsigned short* g, unsigned short* l) {
  __builtin_amdgcn_global_load_lds(
      (const __attribute__((address_space(1))) unsigned int*)g,
      (__attribute__((address_space(3))) unsigned int*)l, 16, 0, 0);
}

// 128x128 tile worth of MFMA from one LDS A/B buffer (BK=32) — used by gemm_xp
__device__ __forceinline__ void mfma_tile(const unsigned short* as, const unsigned short* bs,
                                          int w, int quad, int l15, f32x4 (&acc)[2][8]) {
  bf16x8 af[2], bfr[8];
#pragma unroll
  for (int mt = 0; mt < 2; ++mt)
    af[mt] = *(const bf16x8*)&as[(w * 32 + mt * 16 + l15) * 32 + quad * 8];
#pragma unroll
  for (int nt = 0; nt < 8; ++nt)
    bfr[nt] = *(const bf16x8*)&bs[(nt * 16 + l15) * 32 + quad * 8];
#pragma unroll
  for (int mt = 0; mt < 2; ++mt)
#pragma unroll
    for (int nt = 0; nt < 8; ++nt)
      acc[mt][nt] = __builtin_amdgcn_mfma_f32_16x16x32_bf16(af[mt], bfr[nt], acc[mt][nt], 0, 0, 0);
}

// Convert inputs [81920,561] f32 -> bf16 zero-padded [81920,576]
__global__ void conv_inputs(const float* __restrict__ in, unsigned short* __restrict__ Ain) {
  int idx = blockIdx.x * 256 + threadIdx.x;  // over 81920*144, 4 elems each
  if (idx >= 81920 * 144) return;
  int c4 = (idx % 144) * 4;
  size_t row = idx / 144;
  const float* src = in + row * 561 + c4;
  ushort4 v;
  v.x = f2bf(c4 + 0 < 561 ? src[0] : 0.f);
  v.y = f2bf(c4 + 1 < 561 ? src[1] : 0.f);
  v.z = f2bf(c4 + 2 < 561 ? src[2] : 0.f);
  v.w = f2bf(c4 + 3 < 561 ? src[3] : 0.f);
  *(ushort4*)(Ain + row * 576 + c4) = v;
}

// Build bf16 weights + combined biases:
//  Wib [256][576], W0p/W1p [1024][512] gate-permuted (n' -> h=(n'>>7)*32+(n'&31),
//  g=(n'>>5)&3, src row g*256+h), Wob [16][256], bc0/bc1 [1024] = bih+bhh (f32).
__global__ void conv_weights(const float* __restrict__ Winp,
                             const float* __restrict__ Wih0, const float* __restrict__ Whh0,
                             const float* __restrict__ Wih1, const float* __restrict__ Whh1,
                             const float* __restrict__ Wout,
                             const float* __restrict__ bih0, const float* __restrict__ bhh0,
                             const float* __restrict__ bih1, const float* __restrict__ bhh1,
                             unsigned short* __restrict__ Wib,
                             unsigned short* __restrict__ W0p,
                             unsigned short* __restrict__ W1p,
                             unsigned short* __restrict__ Wob,
                             float* __restrict__ bc0, float* __restrict__ bc1) {
  int idx = blockIdx.x * 256 + threadIdx.x;
  if (idx < 256 * 576) {
    int kk = idx % 576, n = idx / 576;
    Wib[idx] = f2bf(kk < 561 ? Winp[n * 561 + kk] : 0.f);
    return;
  }
  idx -= 256 * 576;
  if (idx < 1024 * 512) {
    int kk = idx % 512, np = idx / 512;
    int h = (np >> 7) * 32 + (np & 31), g = (np >> 5) & 3;
    int sr = g * 256 + h;
    float v = kk < 256 ? Wih0[sr * 256 + kk] : Whh0[sr * 256 + kk - 256];
    W0p[idx] = f2bf(v);
    return;
  }
  idx -= 1024 * 512;
  if (idx < 1024 * 512) {
    int kk = idx % 512, np = idx / 512;
    int h = (np >> 7) * 32 + (np & 31), g = (np >> 5) & 3;
    int sr = g * 256 + h;
    float v = kk < 256 ? Wih1[sr * 256 + kk] : Whh1[sr * 256 + kk - 256];
    W1p[idx] = f2bf(v);
    return;
  }
  idx -= 1024 * 512;
  if (idx < 16 * 256) {
    int kk = idx % 256, o = idx / 256;
    Wob[idx] = f2bf(o < OO ? Wout[o * 256 + kk] : 0.f);
    return;
  }
  idx -= 16 * 256;
  if (idx < 1024) { bc0[idx] = bih0[idx] + bhh0[idx]; return; }
  idx -= 1024;
  if (idx < 1024) { bc1[idx] = bih1[idx] + bhh1[idx]; }
}

// xp GEMM: xp[81920,256] = Ain @ Wib^T + b_inp. M=81920 N=256 K=576. (unchanged)
__global__ __launch_bounds__(256, 2) void gemm_xp(
    const unsigned short* __restrict__ A, const unsigned short* __restrict__ W,
    const float* __restrict__ bias, unsigned short* __restrict__ xp) {
  __shared__ __align__(16) unsigned short As[2][128 * 32];
  __shared__ __align__(16) unsigned short Bs[2][128 * 32];
  const int tid = threadIdx.x;
  const int w = tid >> 6, lane = tid & 63, quad = lane >> 4, l15 = lane & 15;
  const int flat = blockIdx.x;
  const int xcd = flat & 7, kb = flat >> 3;     // kb in [0,160)
  const int nb = kb & 1, mb = xcd * 80 + (kb >> 1);
  const int r0 = tid >> 2, cc = (tid & 3) * 8;

  auto stage = [&](int buf, int k0) {
    gl_lds16(A + (size_t)(mb * 128 + r0) * FP + k0 + cc, &As[buf][tid * 8]);
    gl_lds16(A + (size_t)(mb * 128 + 64 + r0) * FP + k0 + cc, &As[buf][2048 + tid * 8]);
    gl_lds16(W + (size_t)(nb * 128 + r0) * FP + k0 + cc, &Bs[buf][tid * 8]);
    gl_lds16(W + (size_t)(nb * 128 + 64 + r0) * FP + k0 + cc, &Bs[buf][2048 + tid * 8]);
  };

  f32x4 acc[2][8];
#pragma unroll
  for (int i = 0; i < 2; ++i)
#pragma unroll
    for (int j = 0; j < 8; ++j) acc[i][j] = (f32x4){0.f, 0.f, 0.f, 0.f};

  stage(0, 0);
  __syncthreads();
  int cur = 0;
#pragma unroll
  for (int ks = 0; ks < 17; ++ks) {
    stage(cur ^ 1, (ks + 1) * 32);
    mfma_tile(&As[cur][0], &Bs[cur][0], w, quad, l15, acc);
    __syncthreads();
    cur ^= 1;
  }
  mfma_tile(&As[cur][0], &Bs[cur][0], w, quad, l15, acc);

#pragma unroll
  for (int mt = 0; mt < 2; ++mt) {
    int rowb = mb * 128 + w * 32 + mt * 16 + quad * 4;
#pragma unroll
    for (int nt = 0; nt < 8; ++nt) {
      int col = nb * 128 + nt * 16 + l15;
      float bv = bias[col];
#pragma unroll
      for (int r = 0; r < 4; ++r)
        xp[(size_t)(rowb + r) * HH + col] = f2bf(acc[mt][nt][r] + bv);
    }
  }
}

struct RArgs {
  const unsigned short* xp;   // [81920][256], row m = b*TT + t
  unsigned short* hs;         // [(T+1)][B][H], slots 1..T written here
  const unsigned short* W0p;  // [1024][512] gate-permuted
  const unsigned short* W1p;
  const float* bc0;           // [1024] bih0+bhh0, gate-major
  const float* bc1;
  float* hn;                  // [2][B][H] f32 out
  float* cn;
};

// Exchange-free persistent LSTM: 256 blocks, each owns 32 batch rows END-TO-END
// for all T=10 steps, both layers. NO inter-block communication -> no fences,
// no flags, no kernel boundaries -> L2 stays warm the whole recurrence (fix for
// round-4's 822MB refetch storm from agent-fence L2 invalidation).
// Per job: gates[32x1024] = [x(32x256)|h(32x256)] @ W^T. B-frags read DIRECT
// global->VGPR from L2-resident W (no LDS staging, no per-K-step barriers).
// x-frags direct from xp (nontemporal). h0/h1 in LDS (stride 264 = pad vs bank
// conflicts); c0/c1 in registers. acc[2][16] f32x4 = 128 VGPR -> 1 wave/SIMD.
__global__ __launch_bounds__(256, 1) void lstm_rows(RArgs p) {
  __shared__ __align__(16) unsigned short h0l[32 * 264];
  __shared__ __align__(16) unsigned short h1l[32 * 264];
  const int tid = threadIdx.x;
  const int w = tid >> 6, lane = tid & 63, q4 = lane >> 4, l15 = lane & 15;
  const int b0 = blockIdx.x * 32;

  for (int i = tid; i < 32 * 264; i += 256) { h0l[i] = 0; h1l[i] = 0; }

  f32x4 c0r[2][2][2], c1r[2][2][2];
#pragma unroll
  for (int a = 0; a < 2; ++a)
#pragma unroll
    for (int b = 0; b < 2; ++b)
#pragma unroll
      for (int c = 0; c < 2; ++c) {
        c0r[a][b][c] = (f32x4){0.f, 0.f, 0.f, 0.f};
        c1r[a][b][c] = (f32x4){0.f, 0.f, 0.f, 0.f};
      }

  f32x4 acc[2][16];
  const int bofs = (w * 256 + l15) * 512 + q4 * 8;  // b-frag base (shorts)

  auto zacc = [&]() {
#pragma unroll
    for (int i = 0; i < 2; ++i)
#pragma unroll
      for (int j = 0; j < 16; ++j) acc[i][j] = (f32x4){0.f, 0.f, 0.f, 0.f};
  };

  // K-half from global A (xp): 8 K-steps of 32
  auto khalf_glob = [&](const unsigned short* abase, const unsigned short* Wh) {
    const unsigned short* a0 = abase + (size_t)l15 * (TT * HH) + q4 * 8;
    const unsigned short* a1 = abase + (size_t)(16 + l15) * (TT * HH) + q4 * 8;
    const unsigned short* bW = Wh + bofs;
#pragma unroll 4
    for (int ks = 0; ks < 8; ++ks) {
      bf16x8 af0 = __builtin_nontemporal_load((const bf16x8*)(a0 + ks * 32));
      bf16x8 af1 = __builtin_nontemporal_load((const bf16x8*)(a1 + ks * 32));
#pragma unroll
      for (int nf = 0; nf < 16; ++nf) {
        bf16x8 bf = *(const bf16x8*)(bW + nf * 8192 + ks * 32);
        acc[0][nf] = __builtin_amdgcn_mfma_f32_16x16x32_bf16(af0, bf, acc[0][nf], 0, 0, 0);
        acc[1][nf] = __builtin_amdgcn_mfma_f32_16x16x32_bf16(af1, bf, acc[1][nf], 0, 0, 0);
      }
    }
  };

  // K-half from LDS h buffer (stride 264)
  auto khalf_lds = [&](const unsigned short* hl, const unsigned short* Wh) {
    const unsigned short* a0 = hl + l15 * 264 + q4 * 8;
    const unsigned short* a1 = hl + (16 + l15) * 264 + q4 * 8;
    const unsigned short* bW = Wh + bofs;
#pragma unroll 4
    for (int ks = 0; ks < 8; ++ks) {
      bf16x8 af0 = *(const bf16x8*)(a0 + ks * 32);
      bf16x8 af1 = *(const bf16x8*)(a1 + ks * 32);
#pragma unroll
      for (int nf = 0; nf < 16; ++nf) {
        bf16x8 bf = *(const bf16x8*)(bW + nf * 8192 + ks * 32);
        acc[0][nf] = __builtin_amdgcn_mfma_f32_16x16x32_bf16(af0, bf, acc[0][nf], 0, 0, 0);
        acc[1][nf] = __builtin_amdgcn_mfma_f32_16x16x32_bf16(af1, bf, acc[1][nf], 0, 0, 0);
      }
    }
  };

  // Epilogue: gates -> cell update. Thread cells: rows mt*16+q4*4+r,
  // h-cols w*64+hi2*32+lo*16+l15; gate g's frag at nf = hi2*8 + g*2 + lo.
  auto cell = [&](f32x4 (&cr)[2][2][2], const float* bc, unsigned short* hl,
                  unsigned short* hg, float* hf, float* cf) {
#pragma unroll
    for (int mt = 0; mt < 2; ++mt)
#pragma unroll
      for (int hi2 = 0; hi2 < 2; ++hi2)
#pragma unroll
        for (int lo = 0; lo < 2; ++lo) {
          const int hcol = w * 64 + hi2 * 32 + lo * 16 + l15;
          const float bI = bc[hcol];
          const float bF = bc[256 + hcol];
          const float bG = bc[512 + hcol];
          const float bO = bc[768 + hcol];
          const f32x4& xi = acc[mt][hi2 * 8 + 0 + lo];
          const f32x4& xf = acc[mt][hi2 * 8 + 2 + lo];
          const f32x4& xg = acc[mt][hi2 * 8 + 4 + lo];
          const f32x4& xo = acc[mt][hi2 * 8 + 6 + lo];
#pragma unroll
          for (int r = 0; r < 4; ++r) {
            const int row = mt * 16 + q4 * 4 + r;
            const float co = cr[mt][hi2][lo][r];
            const float cnv = sigm(xf[r] + bF) * co + sigm(xi[r] + bI) * tanh_fast(xg[r] + bG);
            const float hnv = sigm(xo[r] + bO) * tanh_fast(cnv);
            cr[mt][hi2][lo][r] = cnv;
            hl[row * 264 + hcol] = f2bf(hnv);
            if (hg) __builtin_nontemporal_store(f2bf(hnv), hg + (size_t)row * HH + hcol);
            if (hf) {
              hf[(size_t)row * HH + hcol] = hnv;
              cf[(size_t)row * HH + hcol] = cnv;
            }
          }
        }
  };

  __syncthreads();   // h0l/h1l zero-init visible

  for (int t = 0; t < TT; ++t) {
    const bool last = (t == TT - 1);
    // ---------------- L0: gates = [xp_t | h0] @ W0^T ----------------
    zacc();
    khalf_glob(p.xp + (size_t)b0 * (TT * HH) + t * HH, p.W0p);       // K 0..255
    khalf_lds(h0l, p.W0p + 256);                                     // K 256..511
    __syncthreads();   // all reads of h0l done before overwrite
    cell(c0r, p.bc0, h0l, nullptr,
         last ? p.hn + (size_t)b0 * HH : nullptr,
         last ? p.cn + (size_t)b0 * HH : nullptr);
    __syncthreads();   // new h0 visible to all waves
    // ---------------- L1: gates = [h0 | h1] @ W1^T ----------------
    zacc();
    khalf_lds(h0l, p.W1p);                                           // K 0..255
    khalf_lds(h1l, p.W1p + 256);                                     // K 256..511
    __syncthreads();   // all reads of h1l done before overwrite
    cell(c1r, p.bc1, h1l,
         p.hs + (size_t)(t + 1) * BB * HH + (size_t)b0 * HH,
         last ? p.hn + (size_t)BB * HH + (size_t)b0 * HH : nullptr,
         last ? p.cn + (size_t)BB * HH + (size_t)b0 * HH : nullptr);
    __syncthreads();   // new h1 visible to all waves
  }
}

// Output projection: out[m=t*B+b][o] = hs[m+B][:] . Wob[o][:] + bout[o] (unchanged)
__global__ __launch_bounds__(256) void out_gemm_mfma(
    const unsigned short* __restrict__ hs,
    const unsigned short* __restrict__ Wob,
    const float* __restrict__ bout,
    float* __restrict__ out) {
  const int tid = threadIdx.x;
  const int w = tid >> 6, lane = tid & 63, quad = lane >> 4, l15 = lane & 15;
  const int m0 = blockIdx.x * 64 + w * 16;
  const unsigned short* arow = hs + (size_t)(m0 + l15 + BB) * HH + quad * 8;
  const unsigned short* brow = Wob + l15 * HH + quad * 8;
  f32x4 acc = (f32x4){0.f, 0.f, 0.f, 0.f};
#pragma unroll
  for (int k0 = 0; k0 < 8; ++k0) {
    bf16x8 a = *(const bf16x8*)(arow + k0 * 32);
    bf16x8 b = *(const bf16x8*)(brow + k0 * 32);
    acc = __builtin_amdgcn_mfma_f32_16x16x32_bf16(a, b, acc, 0, 0, 0);
  }
  const int o = l15;
  if (o < OO) {
    float bv = bout[o];
#pragma unroll
    for (int r = 0; r < 4; ++r) {
      int m = m0 + quad * 4 + r;
      int b = m & (BB - 1);
      int t = m >> 13;
      out[((size_t)b * TT + t) * OO + o] = acc[r] + bv;
    }
  }
}

extern "C" void kernel_launch(void* const* d_in, const int* in_sizes, int n_in,
                              void* d_out, int out_size, void* d_ws, size_t ws_size,
                              hipStream_t stream) {
  const float* inputs = (const float*)d_in[0];
  const float* W_inp  = (const float*)d_in[1];
  const float* b_inp  = (const float*)d_in[2];
  const float* Wih0   = (const float*)d_in[3];
  const float* Whh0   = (const float*)d_in[4];
  const float* bih0   = (const float*)d_in[5];
  const float* bhh0   = (const float*)d_in[6];
  const float* Wih1   = (const float*)d_in[7];
  const float* Whh1   = (const float*)d_in[8];
  const float* bih1   = (const float*)d_in[9];
  const float* bhh1   = (const float*)d_in[10];
  const float* W_out  = (const float*)d_in[11];
  const float* b_out  = (const float*)d_in[12];
  float* out = (float*)d_out;

  char* ws = (char*)d_ws;
  size_t off = 0;
  auto alloc = [&](size_t bytes) {
    char* p = ws + off;
    off += (bytes + 255) & ~(size_t)255;
    return p;
  };
  unsigned short* Ain = (unsigned short*)alloc((size_t)81920 * FP * 2);
  unsigned short* xp  = (unsigned short*)alloc((size_t)81920 * HH * 2);
  unsigned short* Wib = (unsigned short*)alloc((size_t)256 * FP * 2);
  unsigned short* W0p = (unsigned short*)alloc((size_t)1024 * 512 * 2);
  unsigned short* W1p = (unsigned short*)alloc((size_t)1024 * 512 * 2);
  unsigned short* Wob = (unsigned short*)alloc((size_t)16 * HH * 2);
  unsigned short* hs  = (unsigned short*)alloc((size_t)(TT + 1) * BB * HH * 2);
  float* bc0 = (float*)alloc((size_t)1024 * 4);
  float* bc1 = (float*)alloc((size_t)1024 * 4);

  conv_inputs<<<(81920 * 144 + 255) / 256, 256, 0, stream>>>(inputs, Ain);
  {
    int nthr = 256 * 576 + 2 * 1024 * 512 + 16 * 256 + 2048;
    conv_weights<<<(nthr + 255) / 256, 256, 0, stream>>>(
        W_inp, Wih0, Whh0, Wih1, Whh1, W_out, bih0, bhh0, bih1, bhh1,
        Wib, W0p, W1p, Wob, bc0, bc1);
  }

  gemm_xp<<<1280, 256, 0, stream>>>(Ain, Wib, b_inp, xp);

  float* hn_out = out + (size_t)BB * TT * OO;       // h_n [2][B][H]
  float* cn_out = hn_out + (size_t)2 * BB * HH;     // c_n [2][B][H]

  RArgs ra;
  ra.xp = xp; ra.hs = hs;
  ra.W0p = W0p; ra.W1p = W1p;
  ra.bc0 = bc0; ra.bc1 = bc1;
  ra.hn = hn_out; ra.cn = cn_out;
  lstm_rows<<<256, 256, 0, stream>>>(ra);

  out_gemm_mfma<<<1280, 256, 0, stream>>>(hs, Wob, b_out, out);
}